// Round 1
// baseline (1490.777 us; speedup 1.0000x reference)
//
#include <hip/hip_runtime.h>
#include <cstdint>

#define BB 4
#define NN 4096
#define CC 256
#define CRD 128

__device__ __forceinline__ float wredSum(float v){
#pragma unroll
  for (int o=32;o;o>>=1) v += __shfl_down(v,o);
  return v;
}
__device__ __forceinline__ float wredMax(float v){
#pragma unroll
  for (int o=32;o;o>>=1) v = fmaxf(v,__shfl_down(v,o));
  return v;
}
__device__ __forceinline__ int wredSumI(int v){
#pragma unroll
  for (int o=32;o;o>>=1) v += __shfl_down(v,o);
  return v;
}

// ---------------- projection GEMM: out = prelu(X @ W + bias) ----------------
// X: [16384, 256] row-major; W: [256, NC]; out: [16384, NC]; NC in {128, 256}
__global__ __launch_bounds__(256) void proj_kernel(
    const float* __restrict__ X, const float* __restrict__ W,
    const float* __restrict__ bias, const float* __restrict__ alphaP,
    float* __restrict__ out, int NC)
{
  __shared__ float Ast[8][128];
  __shared__ float Bs[8][128];
  const int t  = threadIdx.x;
  const int m0 = blockIdx.y * 128;
  const int n0 = blockIdx.x * 128;
  const int tx = t & 15, ty = t >> 4;
  const int ar = t >> 1, ak = (t & 1) * 4;
  const int bk = t >> 5, bc = (t & 31) * 4;
  float acc[8][8];
#pragma unroll
  for (int i=0;i<8;i++)
#pragma unroll
    for (int j=0;j<8;j++) acc[i][j]=0.f;

  for (int k0=0;k0<CC;k0+=8){
    float4 va = *(const float4*)(X + (size_t)(m0+ar)*CC + k0 + ak);
    float4 vb = *(const float4*)(W + (size_t)(k0+bk)*NC + n0 + bc);
    Ast[ak+0][ar]=va.x; Ast[ak+1][ar]=va.y; Ast[ak+2][ar]=va.z; Ast[ak+3][ar]=va.w;
    *(float4*)&Bs[bk][bc] = vb;
    __syncthreads();
#pragma unroll
    for (int k=0;k<8;k++){
      float a[8], b[8];
      *(float4*)&a[0] = *(const float4*)&Ast[k][ty*8];
      *(float4*)&a[4] = *(const float4*)&Ast[k][ty*8+4];
      *(float4*)&b[0] = *(const float4*)&Bs[k][tx*8];
      *(float4*)&b[4] = *(const float4*)&Bs[k][tx*8+4];
#pragma unroll
      for (int i=0;i<8;i++)
#pragma unroll
        for (int j=0;j<8;j++) acc[i][j] = fmaf(a[i], b[j], acc[i][j]);
    }
    __syncthreads();
  }
  const float al = alphaP[0];
#pragma unroll
  for (int i=0;i<8;i++){
    const size_t r = (size_t)(m0 + ty*8 + i);
#pragma unroll
    for (int j=0;j<8;j+=4){
      float c[4];
#pragma unroll
      for (int q=0;q<4;q++){
        float u = acc[i][j+q] + bias[n0 + tx*8 + j + q];
        c[q] = u >= 0.f ? u : al*u;
      }
      *(float4*)(out + r*NC + n0 + tx*8 + j) = make_float4(c[0],c[1],c[2],c[3]);
    }
  }
}

// ---------------- QK^T: S[i][j] = sum_d e1[i][d]*e2[j][d] ----------------
// per batch via blockIdx.z (grid.z=1 with pre-offset pointers also works)
__global__ __launch_bounds__(256) void qk_kernel(
    const float* __restrict__ E1, const float* __restrict__ E2,
    float* __restrict__ S)
{
  const int z = blockIdx.z;
  const float* e1 = E1 + (size_t)z * NN * CRD;
  const float* e2 = E2 + (size_t)z * NN * CRD;
  float* s = S + (size_t)z * NN * NN;

  __shared__ float Ast[8][128];
  __shared__ float Bst[8][128];
  const int t  = threadIdx.x;
  const int m0 = blockIdx.y * 128;
  const int n0 = blockIdx.x * 128;
  const int tx = t & 15, ty = t >> 4;
  const int ar = t >> 1, ak = (t & 1) * 4;  // ar = row (A) / col (B), ak = k offset
  float acc[8][8];
#pragma unroll
  for (int i=0;i<8;i++)
#pragma unroll
    for (int j=0;j<8;j++) acc[i][j]=0.f;

  for (int k0=0;k0<CRD;k0+=8){
    float4 va = *(const float4*)(e1 + (size_t)(m0+ar)*CRD + k0 + ak);
    float4 vb = *(const float4*)(e2 + (size_t)(n0+ar)*CRD + k0 + ak);
    Ast[ak+0][ar]=va.x; Ast[ak+1][ar]=va.y; Ast[ak+2][ar]=va.z; Ast[ak+3][ar]=va.w;
    Bst[ak+0][ar]=vb.x; Bst[ak+1][ar]=vb.y; Bst[ak+2][ar]=vb.z; Bst[ak+3][ar]=vb.w;
    __syncthreads();
#pragma unroll
    for (int k=0;k<8;k++){
      float a[8], b[8];
      *(float4*)&a[0] = *(const float4*)&Ast[k][ty*8];
      *(float4*)&a[4] = *(const float4*)&Ast[k][ty*8+4];
      *(float4*)&b[0] = *(const float4*)&Bst[k][tx*8];
      *(float4*)&b[4] = *(const float4*)&Bst[k][tx*8+4];
#pragma unroll
      for (int i=0;i<8;i++)
#pragma unroll
        for (int j=0;j<8;j++) acc[i][j] = fmaf(a[i], b[j], acc[i][j]);
    }
    __syncthreads();
  }
#pragma unroll
  for (int i=0;i<8;i++){
    const size_t r = (size_t)(m0 + ty*8 + i);
#pragma unroll
    for (int j=0;j<8;j+=4){
      *(float4*)(s + r*NN + n0 + tx*8 + j) =
        make_float4(acc[i][j],acc[i][j+1],acc[i][j+2],acc[i][j+3]);
    }
  }
}

// ---------------- sparsemax tau per row (Michelot fixed point) ----------------
// One block per row. Stores T[row] = rowmax + tau, so p = max(s - T, 0).
__global__ __launch_bounds__(256) void sparsemax_kernel(
    const float* __restrict__ S, float* __restrict__ Tout)
{
  const int row = blockIdx.x;
  const float* s = S + (size_t)row * NN;
  const int t = threadIdx.x;
  const int lane = t & 63, wid = t >> 6;
  __shared__ float redf[4];
  __shared__ int   redi[4];

  float v[16];
  float mx = -1e30f;
#pragma unroll
  for (int j=0;j<16;j++){ v[j] = s[t + 256*j]; mx = fmaxf(mx, v[j]); }
  mx = wredMax(mx);
  if (lane==0) redf[wid] = mx;
  __syncthreads();
  mx = fmaxf(fmaxf(redf[0],redf[1]), fmaxf(redf[2],redf[3]));
  __syncthreads();
#pragma unroll
  for (int j=0;j<16;j++) v[j] -= mx;

  float ssum = 0.f;
#pragma unroll
  for (int j=0;j<16;j++) ssum += v[j];
  ssum = wredSum(ssum);
  if (lane==0) redf[wid] = ssum;
  __syncthreads();
  float tau = (redf[0]+redf[1]+redf[2]+redf[3] - 1.f) * (1.f/(float)NN);
  __syncthreads();

  int cnt = NN;
  for (int iter=0; iter<128; ++iter){
    float ps = 0.f; int pc = 0;
#pragma unroll
    for (int j=0;j<16;j++){
      if (v[j] > tau){ ps += v[j]; pc++; }
    }
    ps = wredSum(ps); pc = wredSumI(pc);
    if (lane==0){ redf[wid] = ps; redi[wid] = pc; }
    __syncthreads();
    float S4 = redf[0]+redf[1]+redf[2]+redf[3];
    int   C4 = redi[0]+redi[1]+redi[2]+redi[3];
    __syncthreads();
    tau = (S4 - 1.f) / (float)C4;
    if (C4 == cnt) break;
    cnt = C4;
  }
  if (t==0) Tout[row] = tau + mx;
}

// ---------------- PV: out = relu(S - T) @ V + Xres ----------------
__global__ __launch_bounds__(256) void pv_kernel(
    const float* __restrict__ S, const float* __restrict__ Tt,
    const float* __restrict__ V, const float* __restrict__ Xr,
    float* __restrict__ out)
{
  const int z = blockIdx.z;
  const float* s  = S  + (size_t)z * NN * NN;
  const float* Tz = Tt + (size_t)z * NN;
  const float* vv = V  + (size_t)z * NN * CC;
  const float* xr = Xr + (size_t)z * NN * CC;
  float* o = out + (size_t)z * NN * CC;

  __shared__ float Ast[16][64];
  __shared__ float Bs[16][64];
  const int t  = threadIdx.x;
  const int m0 = blockIdx.y * 64;
  const int n0 = blockIdx.x * 64;
  const int tx = t & 15, ty = t >> 4;
  const int ar = t >> 2, ak = (t & 3) * 4;
  const int bk = t >> 4, bc = (t & 15) * 4;
  const float Trow = Tz[m0 + ar];

  float acc[4][4];
#pragma unroll
  for (int i=0;i<4;i++)
#pragma unroll
    for (int j=0;j<4;j++) acc[i][j]=0.f;

  for (int k0=0;k0<NN;k0+=16){
    float4 va = *(const float4*)(s + (size_t)(m0+ar)*NN + k0 + ak);
    float4 vb = *(const float4*)(vv + (size_t)(k0+bk)*CC + n0 + bc);
    Ast[ak+0][ar] = fmaxf(va.x - Trow, 0.f);
    Ast[ak+1][ar] = fmaxf(va.y - Trow, 0.f);
    Ast[ak+2][ar] = fmaxf(va.z - Trow, 0.f);
    Ast[ak+3][ar] = fmaxf(va.w - Trow, 0.f);
    *(float4*)&Bs[bk][bc] = vb;
    __syncthreads();
#pragma unroll
    for (int k=0;k<16;k++){
      float a[4], b[4];
      *(float4*)&a[0] = *(const float4*)&Ast[k][ty*4];
      *(float4*)&b[0] = *(const float4*)&Bs[k][tx*4];
#pragma unroll
      for (int i=0;i<4;i++)
#pragma unroll
        for (int j=0;j<4;j++) acc[i][j] = fmaf(a[i], b[j], acc[i][j]);
    }
    __syncthreads();
  }
#pragma unroll
  for (int i=0;i<4;i++){
    const size_t r = (size_t)(m0 + ty*4 + i);
#pragma unroll
    for (int j=0;j<4;j+=4){
      float4 res;
      const float4 xv = *(const float4*)(xr + r*CC + n0 + tx*4);
      res.x = acc[i][0] + xv.x;
      res.y = acc[i][1] + xv.y;
      res.z = acc[i][2] + xv.z;
      res.w = acc[i][3] + xv.w;
      *(float4*)(o + r*CC + n0 + tx*4) = res;
    }
  }
}

extern "C" void kernel_launch(void* const* d_in, const int* in_sizes, int n_in,
                              void* d_out, int out_size, void* d_ws, size_t ws_size,
                              hipStream_t stream) {
  const float* x  = (const float*)d_in[0];
  const float* W1 = (const float*)d_in[1];
  const float* b1 = (const float*)d_in[2];
  const float* a1 = (const float*)d_in[3];
  const float* W2 = (const float*)d_in[4];
  const float* b2 = (const float*)d_in[5];
  const float* a2 = (const float*)d_in[6];
  const float* Wa = (const float*)d_in[7];
  const float* ba = (const float*)d_in[8];
  const float* aa = (const float*)d_in[9];
  float* out = (float*)d_out;
  float* ws  = (float*)d_ws;

  // workspace layout (floats)
  float* e1 = ws;                                   // 4*4096*128 = 2,097,152
  float* e2 = e1 + (size_t)BB*NN*CRD;               // 2,097,152
  float* av = e2 + (size_t)BB*NN*CRD;               // 4*4096*256 = 4,194,304
  float* Tt = av + (size_t)BB*NN*CC;                // 16384 (full) or 4096 (per-batch)

  const size_t baseFloats = (size_t)2*BB*NN*CRD + (size_t)BB*NN*CC;
  const size_t fullFloats = baseFloats + (size_t)BB*NN + (size_t)BB*NN*NN;
  const bool full = ws_size >= fullFloats * sizeof(float);

  dim3 blk(256);
  // projections over all batches at once (M = 16384)
  proj_kernel<<<dim3(1,128,1), blk, 0, stream>>>(x, W1, b1, a1, e1, CRD);
  proj_kernel<<<dim3(1,128,1), blk, 0, stream>>>(x, W2, b2, a2, e2, CRD);
  proj_kernel<<<dim3(2,128,1), blk, 0, stream>>>(x, Wa, ba, aa, av, CC);

  if (full) {
    float* sc = Tt + (size_t)BB*NN;
    qk_kernel<<<dim3(32,32,4), blk, 0, stream>>>(e1, e2, sc);
    sparsemax_kernel<<<dim3(BB*NN,1,1), blk, 0, stream>>>(sc, Tt);
    pv_kernel<<<dim3(4,64,4), blk, 0, stream>>>(sc, Tt, av, x, out);
  } else {
    float* sc = Tt + (size_t)NN;  // per-batch T (4096) then score (4096*4096)
    for (int b=0;b<BB;b++){
      const size_t eo = (size_t)b*NN*CRD;
      const size_t co = (size_t)b*NN*CC;
      qk_kernel<<<dim3(32,32,1), blk, 0, stream>>>(e1+eo, e2+eo, sc);
      sparsemax_kernel<<<dim3(NN,1,1), blk, 0, stream>>>(sc, Tt);
      pv_kernel<<<dim3(4,64,1), blk, 0, stream>>>(sc, Tt, av+co, x+co, out+co);
    }
  }
}

// Round 3
// 474.182 us; speedup vs baseline: 3.1439x; 3.1439x over previous
//
#include <hip/hip_runtime.h>
#include <cstdint>

#define BB 4
#define NN 4096
#define CCH 256

typedef __attribute__((ext_vector_type(8))) short bf16x8;
typedef __attribute__((ext_vector_type(4))) float f32x4;
typedef __attribute__((ext_vector_type(8))) unsigned short us8;

__device__ __forceinline__ unsigned short bf16rn(float f){
  unsigned u = __float_as_uint(f);
  unsigned r = u + 0x7FFFu + ((u>>16)&1u);
  return (unsigned short)(r>>16);
}
__device__ __forceinline__ float bf16tof(unsigned short h){
  return __uint_as_float(((unsigned)h)<<16);
}
__device__ __forceinline__ void gl_lds16(const void* g, void* l){
  __builtin_amdgcn_global_load_lds(
    (const __attribute__((address_space(1))) void*)g,
    (__attribute__((address_space(3))) void*)l, 16, 0, 0);
}

__device__ __forceinline__ float wredSum(float v){
#pragma unroll
  for (int o=32;o;o>>=1) v += __shfl_down(v,o);
  return v;
}
__device__ __forceinline__ float wredMax(float v){
#pragma unroll
  for (int o=32;o;o>>=1) v = fmaxf(v,__shfl_down(v,o));
  return v;
}
__device__ __forceinline__ int wredSumI(int v){
#pragma unroll
  for (int o=32;o;o>>=1) v += __shfl_down(v,o);
  return v;
}

// ---------------- projection GEMM: prelu(X @ W + bias) ----------------
// MODE 0: NC=128, write bf16 hi|lo into e [16384][256]
// MODE 1: NC=256, write bf16 V^T into Vt [B][256][4096]
template<int NC, int MODE>
__global__ __launch_bounds__(256) void proj_kernel(
    const float* __restrict__ X, const float* __restrict__ W,
    const float* __restrict__ bias, const float* __restrict__ alphaP,
    unsigned short* __restrict__ dst)
{
  __shared__ float Ast[8][128];
  __shared__ float Bs[8][128];
  const int t  = threadIdx.x;
  const int m0 = blockIdx.y * 128;
  const int n0 = blockIdx.x * 128;
  const int tx = t & 15, ty = t >> 4;
  const int ar = t >> 1, ak = (t & 1) * 4;
  const int bk = t >> 5, bc = (t & 31) * 4;
  float acc[8][8];
#pragma unroll
  for (int i=0;i<8;i++)
#pragma unroll
    for (int j=0;j<8;j++) acc[i][j]=0.f;

  for (int k0=0;k0<CCH;k0+=8){
    float4 va = *(const float4*)(X + (size_t)(m0+ar)*CCH + k0 + ak);
    float4 vb = *(const float4*)(W + (size_t)(k0+bk)*NC + n0 + bc);
    Ast[ak+0][ar]=va.x; Ast[ak+1][ar]=va.y; Ast[ak+2][ar]=va.z; Ast[ak+3][ar]=va.w;
    *(float4*)&Bs[bk][bc] = vb;
    __syncthreads();
#pragma unroll
    for (int k=0;k<8;k++){
      float a[8], b[8];
      *(float4*)&a[0] = *(const float4*)&Ast[k][ty*8];
      *(float4*)&a[4] = *(const float4*)&Ast[k][ty*8+4];
      *(float4*)&b[0] = *(const float4*)&Bs[k][tx*8];
      *(float4*)&b[4] = *(const float4*)&Bs[k][tx*8+4];
#pragma unroll
      for (int i=0;i<8;i++)
#pragma unroll
        for (int j=0;j<8;j++) acc[i][j] = fmaf(a[i], b[j], acc[i][j]);
    }
    __syncthreads();
  }
  const float al = alphaP[0];
  if (MODE == 0){
#pragma unroll
    for (int i=0;i<8;i++){
      const size_t r = (size_t)(m0 + ty*8 + i);
      us8 hv, lv;
#pragma unroll
      for (int q=0;q<8;q++){
        float u = acc[i][q] + bias[n0 + tx*8 + q];
        u = u >= 0.f ? u : al*u;
        unsigned short h = bf16rn(u);
        hv[q] = h;
        lv[q] = bf16rn(u - bf16tof(h));
      }
      *(us8*)(dst + r*256 + n0 + tx*8)       = hv;
      *(us8*)(dst + r*256 + 128 + n0 + tx*8) = lv;
    }
  } else {
    const int b  = m0 >> 12;            // batch (m0 128-aligned, 4096 rows/batch)
    const int nb = (m0 & (NN-1)) + ty*8;
#pragma unroll
    for (int j=0;j<8;j++){
      const int c = n0 + tx*8 + j;
      const float bs = bias[c];
      us8 pv;
#pragma unroll
      for (int i=0;i<8;i++){
        float u = acc[i][j] + bs;
        u = u >= 0.f ? u : al*u;
        pv[i] = bf16rn(u);
      }
      *(us8*)(dst + ((size_t)(b*CCH + c))*NN + nb) = pv;
    }
  }
}

// ---------------- QK^T with split-bf16 MFMA ----------------
// e1,e2: [4096][256] bf16 (cols 0-127 = hi, 128-255 = lo). S: [4096][4096] fp32.
__global__ __launch_bounds__(256) void qk_mfma(
    const unsigned short* __restrict__ e1, const unsigned short* __restrict__ e2,
    float* __restrict__ S)
{
  __shared__ __align__(16) short As[128*64];
  __shared__ __align__(16) short Bs[128*64];
  const int t = threadIdx.x;
  const int m0 = blockIdx.y*128, n0 = blockIdx.x*128;
  const int wid = t>>6, lane = t&63;
  const int wr = wid>>1, wc = wid&1;
  const int fr = lane&15, fq = lane>>4;
  const int r32 = t>>3, seg = t&7;

  f32x4 acc[4][4];
#pragma unroll
  for (int m=0;m<4;m++)
#pragma unroll
    for (int n=0;n<4;n++) acc[m][n] = (f32x4){0.f,0.f,0.f,0.f};

  const int aoff[6] = {0,64,0,64,128,192};
  const int boff[6] = {0,64,128,192,0,64};
#pragma unroll
  for (int s=0;s<6;s++){
#pragma unroll
    for (int i=0;i<4;i++){
      gl_lds16(e1 + (size_t)(m0 + r32 + i*32)*256 + aoff[s] + seg*8,
               &As[(r32 + i*32)*64 + seg*8]);
      gl_lds16(e2 + (size_t)(n0 + r32 + i*32)*256 + boff[s] + seg*8,
               &Bs[(r32 + i*32)*64 + seg*8]);
    }
    __syncthreads();
    bf16x8 af[4][2], bf[4][2];
#pragma unroll
    for (int m=0;m<4;m++)
#pragma unroll
      for (int ks=0;ks<2;ks++)
        af[m][ks] = *(const bf16x8*)&As[(wr*64 + m*16 + fr)*64 + ks*32 + fq*8];
#pragma unroll
    for (int n=0;n<4;n++)
#pragma unroll
      for (int ks=0;ks<2;ks++)
        bf[n][ks] = *(const bf16x8*)&Bs[(wc*64 + n*16 + fr)*64 + ks*32 + fq*8];
#pragma unroll
    for (int m=0;m<4;m++)
#pragma unroll
      for (int n=0;n<4;n++)
#pragma unroll
        for (int ks=0;ks<2;ks++)
          acc[m][n] = __builtin_amdgcn_mfma_f32_16x16x32_bf16(af[m][ks], bf[n][ks], acc[m][n], 0,0,0);
    __syncthreads();
  }
#pragma unroll
  for (int m=0;m<4;m++){
#pragma unroll
    for (int n=0;n<4;n++){
#pragma unroll
      for (int reg=0;reg<4;reg++){
        const int r = m0 + wr*64 + m*16 + fq*4 + reg;
        const int c = n0 + wc*64 + n*16 + fr;
        S[(size_t)r*NN + c] = acc[m][n][reg];
      }
    }
  }
}

// ---------------- sparsemax: row -> P = relu(s - tau) in bf16 ----------------
__global__ __launch_bounds__(256) void sparsemax_p(
    const float* __restrict__ S, unsigned short* __restrict__ P, int strideP)
{
  const int row = blockIdx.x;
  const float2* sp = (const float2*)(S + (size_t)row * NN);
  const int t = threadIdx.x;
  const int lane = t & 63, wid = t >> 6;
  __shared__ float redf[4];
  __shared__ int   redi[4];

  float v[16];
  float mx = -1e30f;
#pragma unroll
  for (int j=0;j<8;j++){
    float2 u = sp[256*j + t];
    v[2*j] = u.x; v[2*j+1] = u.y;
    mx = fmaxf(mx, fmaxf(u.x,u.y));
  }
  mx = wredMax(mx);
  if (lane==0) redf[wid] = mx;
  __syncthreads();
  mx = fmaxf(fmaxf(redf[0],redf[1]), fmaxf(redf[2],redf[3]));
  __syncthreads();
#pragma unroll
  for (int j=0;j<16;j++) v[j] -= mx;

  float ssum = 0.f;
#pragma unroll
  for (int j=0;j<16;j++) ssum += v[j];
  ssum = wredSum(ssum);
  if (lane==0) redf[wid] = ssum;
  __syncthreads();
  float tau = (redf[0]+redf[1]+redf[2]+redf[3] - 1.f) * (1.f/(float)NN);
  __syncthreads();

  int cnt = NN;
  for (int iter=0; iter<128; ++iter){
    float ps = 0.f; int pc = 0;
#pragma unroll
    for (int j=0;j<16;j++){
      if (v[j] > tau){ ps += v[j]; pc++; }
    }
    ps = wredSum(ps); pc = wredSumI(pc);
    if (lane==0){ redf[wid] = ps; redi[wid] = pc; }
    __syncthreads();
    float S4 = redf[0]+redf[1]+redf[2]+redf[3];
    int   C4 = redi[0]+redi[1]+redi[2]+redi[3];
    __syncthreads();
    tau = (S4 - 1.f) / (float)C4;
    if (C4 == cnt) break;
    cnt = C4;
  }
  unsigned int* Pu = (unsigned int*)(P + (size_t)row * strideP);
#pragma unroll
  for (int j=0;j<8;j++){
    float p0 = fmaxf(v[2*j]   - tau, 0.f);
    float p1 = fmaxf(v[2*j+1] - tau, 0.f);
    Pu[256*j + t] = (unsigned)bf16rn(p0) | ((unsigned)bf16rn(p1) << 16);
  }
}

// ---------------- PV: out = P @ V (+x) via bf16 MFMA ----------------
// MODE 0: z = batch, full K, out = acc + x.   MODE 1: z = K-chunk, atomicAdd.
template<int MODE>
__global__ __launch_bounds__(256) void pv_mfma(
    const unsigned short* __restrict__ Pbase, int strideP,
    const unsigned short* __restrict__ Vt,
    const float* __restrict__ xr, float* __restrict__ out, int ksteps)
{
  __shared__ __align__(16) short As[128*64];
  __shared__ __align__(16) short Bs[128*64];
  const int t = threadIdx.x;
  const int n0 = blockIdx.x*128;  // channel tile
  const int m0 = blockIdx.y*128;  // row tile
  const int z  = blockIdx.z;
  const int wid = t>>6, lane = t&63;
  const int wr = wid>>1, wc = wid&1;
  const int fr = lane&15, fq = lane>>4;
  const int r32 = t>>3, seg = t&7;

  const unsigned short* Pp; const unsigned short* Vp;
  const float* xp; float* op; int k0s;
  if (MODE == 0){
    Pp = Pbase + (size_t)z*NN*strideP;
    Vp = Vt + (size_t)z*CCH*NN;
    xp = xr + (size_t)z*NN*CCH;
    op = out + (size_t)z*NN*CCH;
    k0s = 0;
  } else {
    Pp = Pbase; Vp = Vt; xp = nullptr; op = out;
    k0s = z * ksteps;
  }

  f32x4 acc[4][4];
#pragma unroll
  for (int m=0;m<4;m++)
#pragma unroll
    for (int n=0;n<4;n++) acc[m][n] = (f32x4){0.f,0.f,0.f,0.f};

  for (int s=0;s<ksteps;s++){
    const int kk = (k0s + s)*64;
#pragma unroll
    for (int i=0;i<4;i++){
      gl_lds16(Pp + (size_t)(m0 + r32 + i*32)*strideP + kk + seg*8,
               &As[(r32 + i*32)*64 + seg*8]);
      gl_lds16(Vp + (size_t)(n0 + r32 + i*32)*NN + kk + seg*8,
               &Bs[(r32 + i*32)*64 + seg*8]);
    }
    __syncthreads();
    bf16x8 af[4][2], bf[4][2];
#pragma unroll
    for (int m=0;m<4;m++)
#pragma unroll
      for (int ks=0;ks<2;ks++)
        af[m][ks] = *(const bf16x8*)&As[(wr*64 + m*16 + fr)*64 + ks*32 + fq*8];
#pragma unroll
    for (int n=0;n<4;n++)
#pragma unroll
      for (int ks=0;ks<2;ks++)
        bf[n][ks] = *(const bf16x8*)&Bs[(wc*64 + n*16 + fr)*64 + ks*32 + fq*8];
#pragma unroll
    for (int m=0;m<4;m++)
#pragma unroll
      for (int n=0;n<4;n++)
#pragma unroll
        for (int ks=0;ks<2;ks++)
          acc[m][n] = __builtin_amdgcn_mfma_f32_16x16x32_bf16(af[m][ks], bf[n][ks], acc[m][n], 0,0,0);
    __syncthreads();
  }
#pragma unroll
  for (int m=0;m<4;m++){
#pragma unroll
    for (int n=0;n<4;n++){
#pragma unroll
      for (int reg=0;reg<4;reg++){
        const int r = m0 + wr*64 + m*16 + fq*4 + reg;
        const int c = n0 + wc*64 + n*16 + fr;
        if (MODE == 0)
          op[(size_t)r*CCH + c] = acc[m][n][reg] + xp[(size_t)r*CCH + c];
        else
          atomicAdd(&op[(size_t)r*CCH + c], acc[m][n][reg]);
      }
    }
  }
}

__global__ __launch_bounds__(256) void copy_x(const float* __restrict__ x, float* __restrict__ out, int n4){
  const int stride = gridDim.x * blockDim.x;
  for (int i = blockIdx.x*blockDim.x + threadIdx.x; i < n4; i += stride)
    ((float4*)out)[i] = ((const float4*)x)[i];
}

extern "C" void kernel_launch(void* const* d_in, const int* in_sizes, int n_in,
                              void* d_out, int out_size, void* d_ws, size_t ws_size,
                              hipStream_t stream) {
  const float* x  = (const float*)d_in[0];
  const float* W1 = (const float*)d_in[1];
  const float* b1 = (const float*)d_in[2];
  const float* a1 = (const float*)d_in[3];
  const float* W2 = (const float*)d_in[4];
  const float* b2 = (const float*)d_in[5];
  const float* a2 = (const float*)d_in[6];
  const float* Wa = (const float*)d_in[7];
  const float* ba = (const float*)d_in[8];
  const float* aa = (const float*)d_in[9];
  float* out = (float*)d_out;

  // workspace layout
  unsigned short* e1s = (unsigned short*)d_ws;                 // 16384*256 bf16 (hi|lo)
  unsigned short* e2s = e1s + (size_t)16384*256;               // 16384*256
  unsigned short* Vt  = e2s + (size_t)16384*256;               // 4*256*4096 bf16
  float* Sb = (float*)(Vt + (size_t)BB*CCH*NN);                // 4096*4096 fp32 (per batch)
  unsigned short* Pall = (unsigned short*)(Sb + (size_t)NN*NN);// 4*4096*4096 bf16 (MID only)

  const size_t bytesBase = (size_t)3*16384*256*2;                    // 25,165,824
  const size_t bytesS    = (size_t)NN*NN*4;                          // 67,108,864
  const size_t bytesPall = (size_t)BB*NN*NN*2;                       // 134,217,728
  const bool mid = ws_size >= bytesBase + bytesS + bytesPall;

  dim3 blk(256);
  proj_kernel<128,0><<<dim3(1,128,1), blk, 0, stream>>>(x, W1, b1, a1, e1s);
  proj_kernel<128,0><<<dim3(1,128,1), blk, 0, stream>>>(x, W2, b2, a2, e2s);
  proj_kernel<256,1><<<dim3(2,128,1), blk, 0, stream>>>(x, Wa, ba, aa, Vt);

  if (mid) {
    for (int b=0;b<BB;b++){
      const unsigned short* e1b = e1s + (size_t)b*NN*256;
      const unsigned short* e2b = e2s + (size_t)b*NN*256;
      qk_mfma<<<dim3(32,32,1), blk, 0, stream>>>(e1b, e2b, Sb);
      sparsemax_p<<<dim3(NN,1,1), blk, 0, stream>>>(Sb, Pall + (size_t)b*NN*NN, NN);
    }
    pv_mfma<0><<<dim3(2,32,BB), blk, 0, stream>>>(Pall, NN, Vt, x, out, NN/64);
  } else {
    copy_x<<<dim3(2048,1,1), blk, 0, stream>>>(x, out, BB*NN*CCH/4);
    for (int b=0;b<BB;b++){
      const unsigned short* e1b = e1s + (size_t)b*NN*256;
      const unsigned short* e2b = e2s + (size_t)b*NN*256;
      qk_mfma<<<dim3(32,32,1), blk, 0, stream>>>(e1b, e2b, Sb);
      sparsemax_p<<<dim3(NN,1,1), blk, 0, stream>>>(Sb, (unsigned short*)Sb, 2*NN);
      pv_mfma<1><<<dim3(2,32,4), blk, 0, stream>>>((const unsigned short*)Sb, 2*NN,
          Vt + (size_t)b*CCH*NN, nullptr, out + (size_t)b*NN*CCH, (NN/64)/4);
    }
  }
}

// Round 4
// 429.112 us; speedup vs baseline: 3.4741x; 1.1050x over previous
//
#include <hip/hip_runtime.h>
#include <cstdint>

#define BB 4
#define NN 4096
#define CCH 256

typedef __attribute__((ext_vector_type(8))) short bf16x8;
typedef __attribute__((ext_vector_type(4))) float f32x4;
typedef __attribute__((ext_vector_type(8))) unsigned short us8;

__device__ __forceinline__ unsigned short bf16rn(float f){
  unsigned u = __float_as_uint(f);
  unsigned r = u + 0x7FFFu + ((u>>16)&1u);
  return (unsigned short)(r>>16);
}
__device__ __forceinline__ float bf16tof(unsigned short h){
  return __uint_as_float(((unsigned)h)<<16);
}
__device__ __forceinline__ void gl_lds16(const void* g, void* l){
  __builtin_amdgcn_global_load_lds(
    (const __attribute__((address_space(1))) void*)g,
    (__attribute__((address_space(3))) void*)l, 16, 0, 0);
}

__device__ __forceinline__ float wredSum(float v){
#pragma unroll
  for (int o=32;o;o>>=1) v += __shfl_down(v,o);
  return v;
}
__device__ __forceinline__ float wredMax(float v){
#pragma unroll
  for (int o=32;o;o>>=1) v = fmaxf(v,__shfl_down(v,o));
  return v;
}
__device__ __forceinline__ int wredSumI(int v){
#pragma unroll
  for (int o=32;o;o>>=1) v += __shfl_down(v,o);
  return v;
}

// ------- fused e1/e2 projection: prelu(X@W+b) -> bf16 hi|lo [16384][256] -------
// grid (2, 128): blockIdx.x selects projection (fills all 256 CUs)
__global__ __launch_bounds__(256) void proj_e_kernel(
    const float* __restrict__ X,
    const float* __restrict__ W1, const float* __restrict__ b1, const float* __restrict__ a1,
    const float* __restrict__ W2, const float* __restrict__ b2, const float* __restrict__ a2,
    unsigned short* __restrict__ e1, unsigned short* __restrict__ e2)
{
  const float* W  = blockIdx.x ? W2 : W1;
  const float* bi = blockIdx.x ? b2 : b1;
  const float* ap = blockIdx.x ? a2 : a1;
  unsigned short* dst = blockIdx.x ? e2 : e1;

  __shared__ float Ast[8][128];
  __shared__ float Bs[8][128];
  const int t  = threadIdx.x;
  const int m0 = blockIdx.y * 128;
  const int tx = t & 15, ty = t >> 4;
  const int ar = t >> 1, ak = (t & 1) * 4;
  const int bk = t >> 5, bc = (t & 31) * 4;
  float acc[8][8];
#pragma unroll
  for (int i=0;i<8;i++)
#pragma unroll
    for (int j=0;j<8;j++) acc[i][j]=0.f;

  for (int k0=0;k0<CCH;k0+=8){
    float4 va = *(const float4*)(X + (size_t)(m0+ar)*CCH + k0 + ak);
    float4 vb = *(const float4*)(W + (size_t)(k0+bk)*128 + bc);
    Ast[ak+0][ar]=va.x; Ast[ak+1][ar]=va.y; Ast[ak+2][ar]=va.z; Ast[ak+3][ar]=va.w;
    *(float4*)&Bs[bk][bc] = vb;
    __syncthreads();
#pragma unroll
    for (int k=0;k<8;k++){
      float a[8], b[8];
      *(float4*)&a[0] = *(const float4*)&Ast[k][ty*8];
      *(float4*)&a[4] = *(const float4*)&Ast[k][ty*8+4];
      *(float4*)&b[0] = *(const float4*)&Bs[k][tx*8];
      *(float4*)&b[4] = *(const float4*)&Bs[k][tx*8+4];
#pragma unroll
      for (int i=0;i<8;i++)
#pragma unroll
        for (int j=0;j<8;j++) acc[i][j] = fmaf(a[i], b[j], acc[i][j]);
    }
    __syncthreads();
  }
  const float al = ap[0];
#pragma unroll
  for (int i=0;i<8;i++){
    const size_t r = (size_t)(m0 + ty*8 + i);
    us8 hv, lv;
#pragma unroll
    for (int q=0;q<8;q++){
      float u = acc[i][q] + bi[tx*8 + q];
      u = u >= 0.f ? u : al*u;
      unsigned short h = bf16rn(u);
      hv[q] = h;
      lv[q] = bf16rn(u - bf16tof(h));
    }
    *(us8*)(dst + r*256 + tx*8)       = hv;
    *(us8*)(dst + r*256 + 128 + tx*8) = lv;
  }
}

// ------- value projection: prelu(X@Wa+ba) -> bf16 V^T [B][256][4096] -------
__global__ __launch_bounds__(256) void proj_v_kernel(
    const float* __restrict__ X, const float* __restrict__ W,
    const float* __restrict__ bias, const float* __restrict__ alphaP,
    unsigned short* __restrict__ dst)
{
  __shared__ float Ast[8][128];
  __shared__ float Bs[8][128];
  const int t  = threadIdx.x;
  const int m0 = blockIdx.y * 128;
  const int n0 = blockIdx.x * 128;
  const int tx = t & 15, ty = t >> 4;
  const int ar = t >> 1, ak = (t & 1) * 4;
  const int bk = t >> 5, bc = (t & 31) * 4;
  float acc[8][8];
#pragma unroll
  for (int i=0;i<8;i++)
#pragma unroll
    for (int j=0;j<8;j++) acc[i][j]=0.f;

  for (int k0=0;k0<CCH;k0+=8){
    float4 va = *(const float4*)(X + (size_t)(m0+ar)*CCH + k0 + ak);
    float4 vb = *(const float4*)(W + (size_t)(k0+bk)*CCH + n0 + bc);
    Ast[ak+0][ar]=va.x; Ast[ak+1][ar]=va.y; Ast[ak+2][ar]=va.z; Ast[ak+3][ar]=va.w;
    *(float4*)&Bs[bk][bc] = vb;
    __syncthreads();
#pragma unroll
    for (int k=0;k<8;k++){
      float a[8], b[8];
      *(float4*)&a[0] = *(const float4*)&Ast[k][ty*8];
      *(float4*)&a[4] = *(const float4*)&Ast[k][ty*8+4];
      *(float4*)&b[0] = *(const float4*)&Bs[k][tx*8];
      *(float4*)&b[4] = *(const float4*)&Bs[k][tx*8+4];
#pragma unroll
      for (int i=0;i<8;i++)
#pragma unroll
        for (int j=0;j<8;j++) acc[i][j] = fmaf(a[i], b[j], acc[i][j]);
    }
    __syncthreads();
  }
  const float al = alphaP[0];
  const int b  = m0 >> 12;
  const int nb = (m0 & (NN-1)) + ty*8;
#pragma unroll
  for (int j=0;j<8;j++){
    const int c = n0 + tx*8 + j;
    const float bs = bias[c];
    us8 pv;
#pragma unroll
    for (int i=0;i<8;i++){
      float u = acc[i][j] + bs;
      u = u >= 0.f ? u : al*u;
      pv[i] = bf16rn(u);
    }
    *(us8*)(dst + ((size_t)(b*CCH + c))*NN + nb) = pv;
  }
}

// ---------------- QK^T with split-bf16 MFMA, XOR-swizzled LDS ----------------
// e1,e2: [4096][256] bf16 (cols 0-127 hi, 128-255 lo). S: [4096][4096] fp32.
__global__ __launch_bounds__(256) void qk_mfma(
    const unsigned short* __restrict__ e1, const unsigned short* __restrict__ e2,
    float* __restrict__ S)
{
  __shared__ __align__(16) short As[128*64];
  __shared__ __align__(16) short Bs[128*64];
  const int t = threadIdx.x;
  const int m0 = blockIdx.y*128, n0 = blockIdx.x*128;
  const int wid = t>>6, lane = t&63;
  const int wr = wid>>1, wc = wid&1;
  const int fr = lane&15, fq = lane>>4;
  const int r32 = t>>3, seg = t&7;

  f32x4 acc[4][4];
#pragma unroll
  for (int m=0;m<4;m++)
#pragma unroll
    for (int n=0;n<4;n++) acc[m][n] = (f32x4){0.f,0.f,0.f,0.f};

  // term schedule: A staged only when aoff changes (s0:hihi0 s1:hilo0 s2:hihi1
  // s3:hilo1 s4:lohi0 s5:lohi1)
  constexpr int aoff[6] = {0,0,64,64,128,192};
  constexpr int boff[6] = {0,128,64,192,0,64};
#pragma unroll
  for (int s=0;s<6;s++){
#pragma unroll
    for (int i=0;i<4;i++){
      const int rowL = r32 + i*32;
      const int sw = (seg ^ (rowL & 7)) * 8;   // pre-swizzled global granule
      if (s==0 || aoff[s] != aoff[s-1])
        gl_lds16(e1 + (size_t)(m0 + rowL)*256 + aoff[s] + sw, &As[rowL*64 + seg*8]);
      gl_lds16(e2 + (size_t)(n0 + rowL)*256 + boff[s] + sw, &Bs[rowL*64 + seg*8]);
    }
    __syncthreads();
    bf16x8 af[4][2], bf[4][2];
#pragma unroll
    for (int m=0;m<4;m++){
      const int ar_ = wr*64 + m*16 + fr;
#pragma unroll
      for (int ks=0;ks<2;ks++)
        af[m][ks] = *(const bf16x8*)&As[ar_*64 + (((ks*4+fq) ^ (ar_&7))*8)];
    }
#pragma unroll
    for (int n=0;n<4;n++){
      const int br_ = wc*64 + n*16 + fr;
#pragma unroll
      for (int ks=0;ks<2;ks++)
        bf[n][ks] = *(const bf16x8*)&Bs[br_*64 + (((ks*4+fq) ^ (br_&7))*8)];
    }
#pragma unroll
    for (int m=0;m<4;m++)
#pragma unroll
      for (int n=0;n<4;n++)
#pragma unroll
        for (int ks=0;ks<2;ks++)
          acc[m][n] = __builtin_amdgcn_mfma_f32_16x16x32_bf16(af[m][ks], bf[n][ks], acc[m][n], 0,0,0);
    __syncthreads();
  }
#pragma unroll
  for (int m=0;m<4;m++){
#pragma unroll
    for (int n=0;n<4;n++){
#pragma unroll
      for (int reg=0;reg<4;reg++){
        const int r = m0 + wr*64 + m*16 + fq*4 + reg;
        const int c = n0 + wc*64 + n*16 + fr;
        S[(size_t)r*NN + c] = acc[m][n][reg];
      }
    }
  }
}

// ---------------- sparsemax: row -> P = relu(s - tau) in bf16 ----------------
__global__ __launch_bounds__(256) void sparsemax_p(
    const float* __restrict__ S, unsigned short* __restrict__ P, int strideP)
{
  const int row = blockIdx.x;
  const float4* sp = (const float4*)(S + (size_t)row * NN);
  const int t = threadIdx.x;
  const int lane = t & 63, wid = t >> 6;
  __shared__ float redf[4];
  __shared__ int   redi[4];

  float v[16];
  float mx = -1e30f;
#pragma unroll
  for (int j=0;j<4;j++){
    float4 u = sp[256*j + t];
    v[4*j]=u.x; v[4*j+1]=u.y; v[4*j+2]=u.z; v[4*j+3]=u.w;
    mx = fmaxf(mx, fmaxf(fmaxf(u.x,u.y), fmaxf(u.z,u.w)));
  }
  mx = wredMax(mx);
  if (lane==0) redf[wid] = mx;
  __syncthreads();
  mx = fmaxf(fmaxf(redf[0],redf[1]), fmaxf(redf[2],redf[3]));
  __syncthreads();
#pragma unroll
  for (int j=0;j<16;j++) v[j] -= mx;

  float ssum = 0.f;
#pragma unroll
  for (int j=0;j<16;j++) ssum += v[j];
  ssum = wredSum(ssum);
  if (lane==0) redf[wid] = ssum;
  __syncthreads();
  float tau = (redf[0]+redf[1]+redf[2]+redf[3] - 1.f) * (1.f/(float)NN);
  __syncthreads();

  int cnt = NN;
  for (int iter=0; iter<128; ++iter){
    float ps = 0.f; int pc = 0;
#pragma unroll
    for (int j=0;j<16;j++){
      if (v[j] > tau){ ps += v[j]; pc++; }
    }
    ps = wredSum(ps); pc = wredSumI(pc);
    if (lane==0){ redf[wid] = ps; redi[wid] = pc; }
    __syncthreads();
    float S4 = redf[0]+redf[1]+redf[2]+redf[3];
    int   C4 = redi[0]+redi[1]+redi[2]+redi[3];
    __syncthreads();
    tau = (S4 - 1.f) / (float)C4;
    if (C4 == cnt) break;
    cnt = C4;
  }
  uint2* Pu = (uint2*)(P + (size_t)row * strideP);
#pragma unroll
  for (int j=0;j<4;j++){
    float p0 = fmaxf(v[4*j]   - tau, 0.f);
    float p1 = fmaxf(v[4*j+1] - tau, 0.f);
    float p2 = fmaxf(v[4*j+2] - tau, 0.f);
    float p3 = fmaxf(v[4*j+3] - tau, 0.f);
    uint2 w;
    w.x = (unsigned)bf16rn(p0) | ((unsigned)bf16rn(p1) << 16);
    w.y = (unsigned)bf16rn(p2) | ((unsigned)bf16rn(p3) << 16);
    Pu[256*j + t] = w;
  }
}

// ------- PV: out += P @ V via bf16 MFMA, split-K x4, XOR-swizzled LDS -------
// z encodes (batch<<2)|kchunk; out pre-filled with x; atomicAdd epilogue.
__global__ __launch_bounds__(256) void pv_mfma(
    const unsigned short* __restrict__ Pbase, int strideP,
    const unsigned short* __restrict__ Vt,
    float* __restrict__ out, int ksteps)
{
  __shared__ __align__(16) short As[128*64];
  __shared__ __align__(16) short Bs[128*64];
  const int t = threadIdx.x;
  const int n0 = blockIdx.x*128;  // channel tile
  const int m0 = blockIdx.y*128;  // row tile
  const int z  = blockIdx.z;
  const int b  = z >> 2, kc = z & 3;
  const int wid = t>>6, lane = t&63;
  const int wr = wid>>1, wc = wid&1;
  const int fr = lane&15, fq = lane>>4;
  const int r32 = t>>3, seg = t&7;

  const unsigned short* Pp = Pbase + (size_t)b*NN*strideP;
  const unsigned short* Vp = Vt + (size_t)b*CCH*NN;
  float* op = out + (size_t)b*NN*CCH;
  const int k0s = kc * ksteps;

  f32x4 acc[4][4];
#pragma unroll
  for (int m=0;m<4;m++)
#pragma unroll
    for (int n=0;n<4;n++) acc[m][n] = (f32x4){0.f,0.f,0.f,0.f};

  for (int s=0;s<ksteps;s++){
    const int kk = (k0s + s)*64;
#pragma unroll
    for (int i=0;i<4;i++){
      const int rowL = r32 + i*32;
      const int sw = (seg ^ (rowL & 7)) * 8;
      gl_lds16(Pp + (size_t)(m0 + rowL)*strideP + kk + sw, &As[rowL*64 + seg*8]);
      gl_lds16(Vp + (size_t)(n0 + rowL)*NN + kk + sw, &Bs[rowL*64 + seg*8]);
    }
    __syncthreads();
    bf16x8 af[4][2], bf[4][2];
#pragma unroll
    for (int m=0;m<4;m++){
      const int ar_ = wr*64 + m*16 + fr;
#pragma unroll
      for (int ks=0;ks<2;ks++)
        af[m][ks] = *(const bf16x8*)&As[ar_*64 + (((ks*4+fq) ^ (ar_&7))*8)];
    }
#pragma unroll
    for (int n=0;n<4;n++){
      const int br_ = wc*64 + n*16 + fr;
#pragma unroll
      for (int ks=0;ks<2;ks++)
        bf[n][ks] = *(const bf16x8*)&Bs[br_*64 + (((ks*4+fq) ^ (br_&7))*8)];
    }
#pragma unroll
    for (int m=0;m<4;m++)
#pragma unroll
      for (int n=0;n<4;n++)
#pragma unroll
        for (int ks=0;ks<2;ks++)
          acc[m][n] = __builtin_amdgcn_mfma_f32_16x16x32_bf16(af[m][ks], bf[n][ks], acc[m][n], 0,0,0);
    __syncthreads();
  }
#pragma unroll
  for (int m=0;m<4;m++){
#pragma unroll
    for (int n=0;n<4;n++){
#pragma unroll
      for (int reg=0;reg<4;reg++){
        const int r = m0 + wr*64 + m*16 + fq*4 + reg;
        const int c = n0 + wc*64 + n*16 + fr;
        atomicAdd(&op[(size_t)r*CCH + c], acc[m][n][reg]);
      }
    }
  }
}

__global__ __launch_bounds__(256) void copy_x(const float* __restrict__ x, float* __restrict__ out, int n4){
  const int stride = gridDim.x * blockDim.x;
  for (int i = blockIdx.x*blockDim.x + threadIdx.x; i < n4; i += stride)
    ((float4*)out)[i] = ((const float4*)x)[i];
}

extern "C" void kernel_launch(void* const* d_in, const int* in_sizes, int n_in,
                              void* d_out, int out_size, void* d_ws, size_t ws_size,
                              hipStream_t stream) {
  const float* x  = (const float*)d_in[0];
  const float* W1 = (const float*)d_in[1];
  const float* b1 = (const float*)d_in[2];
  const float* a1 = (const float*)d_in[3];
  const float* W2 = (const float*)d_in[4];
  const float* b2 = (const float*)d_in[5];
  const float* a2 = (const float*)d_in[6];
  const float* Wa = (const float*)d_in[7];
  const float* ba = (const float*)d_in[8];
  const float* aa = (const float*)d_in[9];
  float* out = (float*)d_out;

  // workspace layout
  unsigned short* e1s = (unsigned short*)d_ws;                 // 16384*256 bf16 (hi|lo)
  unsigned short* e2s = e1s + (size_t)16384*256;               // 16384*256
  unsigned short* Vt  = e2s + (size_t)16384*256;               // 4*256*4096 bf16
  float* Sb = (float*)(Vt + (size_t)BB*CCH*NN);                // 4096*4096 fp32 (per batch)
  unsigned short* Pall = (unsigned short*)(Sb + (size_t)NN*NN);// 4*4096*4096 bf16 (MID only)

  const size_t bytesBase = (size_t)3*16384*256*2;                    // 25,165,824
  const size_t bytesS    = (size_t)NN*NN*4;                          // 67,108,864
  const size_t bytesPall = (size_t)BB*NN*NN*2;                       // 134,217,728
  const bool mid = ws_size >= bytesBase + bytesS + bytesPall;

  dim3 blk(256);
  proj_e_kernel<<<dim3(2,128,1), blk, 0, stream>>>(x, W1,b1,a1, W2,b2,a2, e1s, e2s);
  proj_v_kernel<<<dim3(2,128,1), blk, 0, stream>>>(x, Wa, ba, aa, Vt);
  copy_x<<<dim3(2048,1,1), blk, 0, stream>>>(x, out, BB*NN*CCH/4);

  if (mid) {
    for (int b=0;b<BB;b++){
      const unsigned short* e1b = e1s + (size_t)b*NN*256;
      const unsigned short* e2b = e2s + (size_t)b*NN*256;
      qk_mfma<<<dim3(32,32,1), blk, 0, stream>>>(e1b, e2b, Sb);
      sparsemax_p<<<dim3(NN,1,1), blk, 0, stream>>>(Sb, Pall + (size_t)b*NN*NN, NN);
    }
    // split-K x4 over all batches: 1024 blocks (4 blocks/CU)
    pv_mfma<<<dim3(2,32,16), blk, 0, stream>>>(Pall, NN, Vt, out, 16);
  } else {
    for (int b=0;b<BB;b++){
      const unsigned short* e1b = e1s + (size_t)b*NN*256;
      const unsigned short* e2b = e2s + (size_t)b*NN*256;
      qk_mfma<<<dim3(32,32,1), blk, 0, stream>>>(e1b, e2b, Sb);
      sparsemax_p<<<dim3(NN,1,1), blk, 0, stream>>>(Sb, (unsigned short*)Sb, 2*NN);
      pv_mfma<<<dim3(2,32,4), blk, 0, stream>>>((const unsigned short*)Sb, 2*NN,
          Vt + (size_t)b*CCH*NN, out + (size_t)b*NN*CCH, 16);
    }
  }
}

// Round 5
// 280.548 us; speedup vs baseline: 5.3138x; 1.5296x over previous
//
#include <hip/hip_runtime.h>
#include <cstdint>

#define BB 4
#define NN 4096
#define CCH 256

typedef __attribute__((ext_vector_type(8))) short bf16x8;
typedef __attribute__((ext_vector_type(4))) float f32x4;
typedef __attribute__((ext_vector_type(8))) unsigned short us8;

__device__ __forceinline__ unsigned short bf16rn(float f){
  unsigned u = __float_as_uint(f);
  unsigned r = u + 0x7FFFu + ((u>>16)&1u);
  return (unsigned short)(r>>16);
}
__device__ __forceinline__ float bf16tof(unsigned short h){
  return __uint_as_float(((unsigned)h)<<16);
}
__device__ __forceinline__ void gl_lds16(const void* g, void* l){
  __builtin_amdgcn_global_load_lds(
    (const __attribute__((address_space(1))) void*)g,
    (__attribute__((address_space(3))) void*)l, 16, 0, 0);
}

__device__ __forceinline__ float wredSum(float v){
#pragma unroll
  for (int o=32;o;o>>=1) v += __shfl_down(v,o);
  return v;
}
__device__ __forceinline__ float wredMax(float v){
#pragma unroll
  for (int o=32;o;o>>=1) v = fmaxf(v,__shfl_down(v,o));
  return v;
}
__device__ __forceinline__ int wredSumI(int v){
#pragma unroll
  for (int o=32;o;o>>=1) v += __shfl_down(v,o);
  return v;
}

// ------- fused e1/e2 projection: prelu(X@W+b) -> bf16 hi|lo [16384][256] -------
__global__ __launch_bounds__(256) void proj_e_kernel(
    const float* __restrict__ X,
    const float* __restrict__ W1, const float* __restrict__ b1, const float* __restrict__ a1,
    const float* __restrict__ W2, const float* __restrict__ b2, const float* __restrict__ a2,
    unsigned short* __restrict__ e1, unsigned short* __restrict__ e2)
{
  const float* W  = blockIdx.x ? W2 : W1;
  const float* bi = blockIdx.x ? b2 : b1;
  const float* ap = blockIdx.x ? a2 : a1;
  unsigned short* dst = blockIdx.x ? e2 : e1;

  __shared__ float Ast[8][128];
  __shared__ float Bs[8][128];
  const int t  = threadIdx.x;
  const int m0 = blockIdx.y * 128;
  const int tx = t & 15, ty = t >> 4;
  const int ar = t >> 1, ak = (t & 1) * 4;
  const int bk = t >> 5, bc = (t & 31) * 4;
  float acc[8][8];
#pragma unroll
  for (int i=0;i<8;i++)
#pragma unroll
    for (int j=0;j<8;j++) acc[i][j]=0.f;

  for (int k0=0;k0<CCH;k0+=8){
    float4 va = *(const float4*)(X + (size_t)(m0+ar)*CCH + k0 + ak);
    float4 vb = *(const float4*)(W + (size_t)(k0+bk)*128 + bc);
    Ast[ak+0][ar]=va.x; Ast[ak+1][ar]=va.y; Ast[ak+2][ar]=va.z; Ast[ak+3][ar]=va.w;
    *(float4*)&Bs[bk][bc] = vb;
    __syncthreads();
#pragma unroll
    for (int k=0;k<8;k++){
      float a[8], b[8];
      *(float4*)&a[0] = *(const float4*)&Ast[k][ty*8];
      *(float4*)&a[4] = *(const float4*)&Ast[k][ty*8+4];
      *(float4*)&b[0] = *(const float4*)&Bs[k][tx*8];
      *(float4*)&b[4] = *(const float4*)&Bs[k][tx*8+4];
#pragma unroll
      for (int i=0;i<8;i++)
#pragma unroll
        for (int j=0;j<8;j++) acc[i][j] = fmaf(a[i], b[j], acc[i][j]);
    }
    __syncthreads();
  }
  const float al = ap[0];
#pragma unroll
  for (int i=0;i<8;i++){
    const size_t r = (size_t)(m0 + ty*8 + i);
    us8 hv, lv;
#pragma unroll
    for (int q=0;q<8;q++){
      float u = acc[i][q] + bi[tx*8 + q];
      u = u >= 0.f ? u : al*u;
      unsigned short h = bf16rn(u);
      hv[q] = h;
      lv[q] = bf16rn(u - bf16tof(h));
    }
    *(us8*)(dst + r*256 + tx*8)       = hv;
    *(us8*)(dst + r*256 + 128 + tx*8) = lv;
  }
}

// ------- value projection: prelu(X@Wa+ba) -> fp32 V [B*N][256] natural -------
__global__ __launch_bounds__(256) void proj_v_kernel(
    const float* __restrict__ X, const float* __restrict__ W,
    const float* __restrict__ bias, const float* __restrict__ alphaP,
    float* __restrict__ dst)
{
  __shared__ float Ast[8][128];
  __shared__ float Bs[8][128];
  const int t  = threadIdx.x;
  const int m0 = blockIdx.y * 128;
  const int n0 = blockIdx.x * 128;
  const int tx = t & 15, ty = t >> 4;
  const int ar = t >> 1, ak = (t & 1) * 4;
  const int bk = t >> 5, bc = (t & 31) * 4;
  float acc[8][8];
#pragma unroll
  for (int i=0;i<8;i++)
#pragma unroll
    for (int j=0;j<8;j++) acc[i][j]=0.f;

  for (int k0=0;k0<CCH;k0+=8){
    float4 va = *(const float4*)(X + (size_t)(m0+ar)*CCH + k0 + ak);
    float4 vb = *(const float4*)(W + (size_t)(k0+bk)*CCH + n0 + bc);
    Ast[ak+0][ar]=va.x; Ast[ak+1][ar]=va.y; Ast[ak+2][ar]=va.z; Ast[ak+3][ar]=va.w;
    *(float4*)&Bs[bk][bc] = vb;
    __syncthreads();
#pragma unroll
    for (int k=0;k<8;k++){
      float a[8], b[8];
      *(float4*)&a[0] = *(const float4*)&Ast[k][ty*8];
      *(float4*)&a[4] = *(const float4*)&Ast[k][ty*8+4];
      *(float4*)&b[0] = *(const float4*)&Bs[k][tx*8];
      *(float4*)&b[4] = *(const float4*)&Bs[k][tx*8+4];
#pragma unroll
      for (int i=0;i<8;i++)
#pragma unroll
        for (int j=0;j<8;j++) acc[i][j] = fmaf(a[i], b[j], acc[i][j]);
    }
    __syncthreads();
  }
  const float al = alphaP[0];
#pragma unroll
  for (int i=0;i<8;i++){
    const size_t r = (size_t)(m0 + ty*8 + i);
#pragma unroll
    for (int j=0;j<8;j+=4){
      float c[4];
#pragma unroll
      for (int q=0;q<4;q++){
        float u = acc[i][j+q] + bias[n0 + tx*8 + j + q];
        c[q] = u >= 0.f ? u : al*u;
      }
      *(float4*)(dst + r*CCH + n0 + tx*8 + j) = make_float4(c[0],c[1],c[2],c[3]);
    }
  }
}

// ---------------- QK^T with split-bf16 MFMA, XOR-swizzled LDS ----------------
__global__ __launch_bounds__(256) void qk_mfma(
    const unsigned short* __restrict__ e1, const unsigned short* __restrict__ e2,
    float* __restrict__ S)
{
  __shared__ __align__(16) short As[128*64];
  __shared__ __align__(16) short Bs[128*64];
  const int t = threadIdx.x;
  const int m0 = blockIdx.y*128, n0 = blockIdx.x*128;
  const int wid = t>>6, lane = t&63;
  const int wr = wid>>1, wc = wid&1;
  const int fr = lane&15, fq = lane>>4;
  const int r32 = t>>3, seg = t&7;

  f32x4 acc[4][4];
#pragma unroll
  for (int m=0;m<4;m++)
#pragma unroll
    for (int n=0;n<4;n++) acc[m][n] = (f32x4){0.f,0.f,0.f,0.f};

  constexpr int aoff[6] = {0,0,64,64,128,192};
  constexpr int boff[6] = {0,128,64,192,0,64};
#pragma unroll
  for (int s=0;s<6;s++){
#pragma unroll
    for (int i=0;i<4;i++){
      const int rowL = r32 + i*32;
      const int sw = (seg ^ (rowL & 7)) * 8;
      if (s==0 || aoff[s] != aoff[s-1])
        gl_lds16(e1 + (size_t)(m0 + rowL)*256 + aoff[s] + sw, &As[rowL*64 + seg*8]);
      gl_lds16(e2 + (size_t)(n0 + rowL)*256 + boff[s] + sw, &Bs[rowL*64 + seg*8]);
    }
    __syncthreads();
    bf16x8 af[4][2], bf[4][2];
#pragma unroll
    for (int m=0;m<4;m++){
      const int ar_ = wr*64 + m*16 + fr;
#pragma unroll
      for (int ks=0;ks<2;ks++)
        af[m][ks] = *(const bf16x8*)&As[ar_*64 + (((ks*4+fq) ^ (ar_&7))*8)];
    }
#pragma unroll
    for (int n=0;n<4;n++){
      const int br_ = wc*64 + n*16 + fr;
#pragma unroll
      for (int ks=0;ks<2;ks++)
        bf[n][ks] = *(const bf16x8*)&Bs[br_*64 + (((ks*4+fq) ^ (br_&7))*8)];
    }
#pragma unroll
    for (int m=0;m<4;m++)
#pragma unroll
      for (int n=0;n<4;n++)
#pragma unroll
        for (int ks=0;ks<2;ks++)
          acc[m][n] = __builtin_amdgcn_mfma_f32_16x16x32_bf16(af[m][ks], bf[n][ks], acc[m][n], 0,0,0);
    __syncthreads();
  }
#pragma unroll
  for (int m=0;m<4;m++){
#pragma unroll
    for (int n=0;n<4;n++){
#pragma unroll
      for (int reg=0;reg<4;reg++){
        const int r = m0 + wr*64 + m*16 + fq*4 + reg;
        const int c = n0 + wc*64 + n*16 + fr;
        S[(size_t)r*NN + c] = acc[m][n][reg];
      }
    }
  }
}

// ------- fused sparsemax + sparse PV: out[r,:] = x[r,:] + sum_k p_k V[i_k,:] -------
// One block per row. Support subset {s > rowmax-1} (math: tau >= max-1 since
// p_max <= 1); Michelot fixed point from that start is exact for any support.
__global__ __launch_bounds__(256) void spv_kernel(
    const float* __restrict__ S, const float* __restrict__ V,
    const float* __restrict__ xr, float* __restrict__ out)
{
  const int row = blockIdx.x;
  const float4* sp = (const float4*)(S + (size_t)row * NN);
  const int t = threadIdx.x;
  const int lane = t & 63, wid = t >> 6;
  __shared__ float redf[4];
  __shared__ int   redi[4];
  __shared__ int   scan[256];
  __shared__ int   pidx[4096];
  __shared__ float pval[4096];

  float v[16];
  float mx = -1e30f;
#pragma unroll
  for (int j=0;j<4;j++){
    float4 u = sp[256*j + t];
    v[4*j]=u.x; v[4*j+1]=u.y; v[4*j+2]=u.z; v[4*j+3]=u.w;
    mx = fmaxf(mx, fmaxf(fmaxf(u.x,u.y), fmaxf(u.z,u.w)));
  }
  mx = wredMax(mx);
  if (lane==0) redf[wid] = mx;
  __syncthreads();
  mx = fmaxf(fmaxf(redf[0],redf[1]), fmaxf(redf[2],redf[3]));
  __syncthreads();
#pragma unroll
  for (int j=0;j<16;j++) v[j] -= mx;

  // Michelot fixed point, started from the filtered superset {v > -1}
  float tau = -1.0f;
  int cnt = -1;
  for (int iter=0; iter<128; ++iter){
    float ps = 0.f; int pc = 0;
#pragma unroll
    for (int j=0;j<16;j++) if (v[j] > tau){ ps += v[j]; pc++; }
    ps = wredSum(ps); pc = wredSumI(pc);
    if (lane==0){ redf[wid] = ps; redi[wid] = pc; }
    __syncthreads();
    float S4 = redf[0]+redf[1]+redf[2]+redf[3];
    int   C4 = redi[0]+redi[1]+redi[2]+redi[3];
    __syncthreads();
    tau = (S4 - 1.f) / (float)C4;
    if (C4 == cnt) break;
    cnt = C4;
  }

  // deterministic nonzero extraction via block inclusive scan
  int lc = 0;
#pragma unroll
  for (int j=0;j<16;j++) if (v[j] > tau) lc++;
  scan[t] = lc;
  __syncthreads();
  for (int off=1; off<256; off<<=1){
    int xs = (t >= off) ? scan[t-off] : 0;
    __syncthreads();
    scan[t] += xs;
    __syncthreads();
  }
  const int K = scan[255];
  int o = scan[t] - lc;
#pragma unroll
  for (int j=0;j<16;j++){
    if (v[j] > tau){
      pidx[o] = 1024*(j>>2) + 4*t + (j&3);
      pval[o] = v[j] - tau;
      o++;
    }
  }
  __syncthreads();

  // sparse PV gather: thread t owns channel t
  float accv = xr[(size_t)row*CCH + t];
  for (int q=0;q<K;q++)
    accv = fmaf(pval[q], V[(size_t)pidx[q]*CCH + t], accv);
  out[(size_t)row*CCH + t] = accv;
}

extern "C" void kernel_launch(void* const* d_in, const int* in_sizes, int n_in,
                              void* d_out, int out_size, void* d_ws, size_t ws_size,
                              hipStream_t stream) {
  const float* x  = (const float*)d_in[0];
  const float* W1 = (const float*)d_in[1];
  const float* b1 = (const float*)d_in[2];
  const float* a1 = (const float*)d_in[3];
  const float* W2 = (const float*)d_in[4];
  const float* b2 = (const float*)d_in[5];
  const float* a2 = (const float*)d_in[6];
  const float* Wa = (const float*)d_in[7];
  const float* ba = (const float*)d_in[8];
  const float* aa = (const float*)d_in[9];
  float* out = (float*)d_out;

  // workspace: e1 8.4MB | e2 8.4MB | V fp32 67MB | S fp32 67MB  (~151MB)
  unsigned short* e1s = (unsigned short*)d_ws;
  unsigned short* e2s = e1s + (size_t)16384*256;
  float* Vf = (float*)(e2s + (size_t)16384*256);
  float* Sb = Vf + (size_t)BB*NN*CCH;

  dim3 blk(256);
  proj_e_kernel<<<dim3(2,128,1), blk, 0, stream>>>(x, W1,b1,a1, W2,b2,a2, e1s, e2s);
  proj_v_kernel<<<dim3(2,128,1), blk, 0, stream>>>(x, Wa, ba, aa, Vf);

  for (int b=0;b<BB;b++){
    const unsigned short* e1b = e1s + (size_t)b*NN*256;
    const unsigned short* e2b = e2s + (size_t)b*NN*256;
    const size_t co = (size_t)b*NN*CCH;
    qk_mfma<<<dim3(32,32,1), blk, 0, stream>>>(e1b, e2b, Sb);
    spv_kernel<<<dim3(NN,1,1), blk, 0, stream>>>(Sb, Vf + co, x + co, out + co);
  }
}

// Round 7
// 226.002 us; speedup vs baseline: 6.5963x; 1.2414x over previous
//
#include <hip/hip_runtime.h>
#include <cstdint>

#define BB 4
#define NN 4096
#define CCH 256

typedef __attribute__((ext_vector_type(8))) short bf16x8;
typedef __attribute__((ext_vector_type(4))) float f32x4;

__device__ __forceinline__ unsigned short bf16rn(float f){
  unsigned u = __float_as_uint(f);
  unsigned r = u + 0x7FFFu + ((u>>16)&1u);
  return (unsigned short)(r>>16);
}
__device__ __forceinline__ float bf16tof(unsigned short h){
  return __uint_as_float(((unsigned)h)<<16);
}
__device__ __forceinline__ void gl_lds16(const void* g, void* l){
  __builtin_amdgcn_global_load_lds(
    (const __attribute__((address_space(1))) void*)g,
    (__attribute__((address_space(3))) void*)l, 16, 0, 0);
}

__device__ __forceinline__ float wredSum(float v){
#pragma unroll
  for (int o=32;o;o>>=1) v += __shfl_down(v,o);
  return v;
}
__device__ __forceinline__ float wredMax(float v){
#pragma unroll
  for (int o=32;o;o>>=1) v = fmaxf(v,__shfl_down(v,o));
  return v;
}
__device__ __forceinline__ int wredSumI(int v){
#pragma unroll
  for (int o=32;o;o>>=1) v += __shfl_down(v,o);
  return v;
}

// stage one 128x64 bf16 tile pair into LDS (linear dest, pre-swizzled source)
__device__ __forceinline__ void stage_pair(
    const unsigned short* __restrict__ a, const unsigned short* __restrict__ b,
    int strideA, int strideB, short* As, short* Bs, int kk, int r32, int seg)
{
#pragma unroll
  for (int i=0;i<4;i++){
    const int rowL = r32 + i*32;
    const int sw = (seg ^ (rowL & 7)) * 8;
    gl_lds16(a + (size_t)rowL*strideA + kk + sw, &As[rowL*64 + seg*8]);
    gl_lds16(b + (size_t)rowL*strideB + kk + sw, &Bs[rowL*64 + seg*8]);
  }
}

__device__ __forceinline__ void frag_mfma(
    const short* As, const short* Bs, int wr, int wc, int fr, int fq,
    f32x4 (&acc)[4][4])
{
  bf16x8 af[4][2], bf[4][2];
#pragma unroll
  for (int m=0;m<4;m++){
    const int ar_ = wr*64 + m*16 + fr;
#pragma unroll
    for (int ks=0;ks<2;ks++)
      af[m][ks] = *(const bf16x8*)&As[ar_*64 + (((ks*4+fq) ^ (ar_&7))*8)];
  }
#pragma unroll
  for (int n=0;n<4;n++){
    const int br_ = wc*64 + n*16 + fr;
#pragma unroll
    for (int ks=0;ks<2;ks++)
      bf[n][ks] = *(const bf16x8*)&Bs[br_*64 + (((ks*4+fq) ^ (br_&7))*8)];
  }
#pragma unroll
  for (int m=0;m<4;m++)
#pragma unroll
    for (int n=0;n<4;n++)
#pragma unroll
      for (int ks=0;ks<2;ks++)
        acc[m][n] = __builtin_amdgcn_mfma_f32_16x16x32_bf16(af[m][ks], bf[n][ks], acc[m][n], 0,0,0);
}

// ---- prep: split x -> xs [16384][768] bf16 (hi 0-255 | lo 256-511 | hi 512-767) ----
__global__ __launch_bounds__(256) void prep_x(
    const float* __restrict__ x, unsigned short* __restrict__ xs)
{
  const int stride = gridDim.x * 256;
  for (int idx = blockIdx.x*256 + threadIdx.x; idx < 16384*64; idx += stride){
    const int r = idx >> 6, c4 = (idx & 63) * 4;
    float4 u = *(const float4*)(x + (size_t)r*256 + c4);
    ushort4 h, l;
    h.x=bf16rn(u.x); l.x=bf16rn(u.x - bf16tof(h.x));
    h.y=bf16rn(u.y); l.y=bf16rn(u.y - bf16tof(h.y));
    h.z=bf16rn(u.z); l.z=bf16rn(u.z - bf16tof(h.z));
    h.w=bf16rn(u.w); l.w=bf16rn(u.w - bf16tof(h.w));
    unsigned short* row = xs + (size_t)r*768;
    *(ushort4*)(row + c4)       = h;
    *(ushort4*)(row + 256 + c4) = l;
    *(ushort4*)(row + 512 + c4) = h;
  }
}

// ---- prep: weights -> Wt [512][768] bf16 (hi | hi | lo), rows = output cols ----
// rows 0-127: W1 cols; 128-255: W2 cols; 256-511: Wa cols
__global__ __launch_bounds__(256) void prep_w(
    const float* __restrict__ W1, const float* __restrict__ W2,
    const float* __restrict__ Wa, unsigned short* __restrict__ Wt)
{
  const int n = blockIdx.x;      // 512
  const int k = threadIdx.x;     // 256
  float w = (n < 128) ? W1[(size_t)k*128 + n]
          : (n < 256) ? W2[(size_t)k*128 + (n-128)]
                      : Wa[(size_t)k*256 + (n-256)];
  unsigned short h = bf16rn(w);
  unsigned short l = bf16rn(w - bf16tof(h));
  unsigned short* row = Wt + (size_t)n*768;
  row[k] = h; row[256+k] = h; row[512+k] = l;
}

// ---- fused projection GEMM (MFMA, K=768 split-bf16): e1x, e2x, V ----
__global__ __launch_bounds__(256) void proj_mfma(
    const unsigned short* __restrict__ xs, const unsigned short* __restrict__ Wt,
    const float* __restrict__ b1, const float* __restrict__ a1,
    const float* __restrict__ b2, const float* __restrict__ a2,
    const float* __restrict__ ba, const float* __restrict__ aa,
    unsigned short* __restrict__ e1x, unsigned short* __restrict__ e2x,
    float* __restrict__ Vf)
{
  __shared__ __align__(16) short As[2][128*64];
  __shared__ __align__(16) short Bs[2][128*64];
  const int t = threadIdx.x;
  const int m0 = blockIdx.y*128, n0 = blockIdx.x*128;
  const int wid = t>>6, lane = t&63;
  const int wr = wid>>1, wc = wid&1;
  const int fr = lane&15, fq = lane>>4;
  const int r32 = t>>3, seg = t&7;

  const unsigned short* ap = xs + (size_t)m0*768;
  const unsigned short* bp = Wt + (size_t)n0*768;

  f32x4 acc[4][4];
#pragma unroll
  for (int m=0;m<4;m++)
#pragma unroll
    for (int n=0;n<4;n++) acc[m][n] = (f32x4){0.f,0.f,0.f,0.f};

  stage_pair(ap, bp, 768, 768, As[0], Bs[0], 0, r32, seg);
  __syncthreads();
#pragma unroll
  for (int s=0;s<12;s++){
    const int cur = s&1;
    if (s<11) stage_pair(ap, bp, 768, 768, As[cur^1], Bs[cur^1], (s+1)*64, r32, seg);
    frag_mfma(As[cur], Bs[cur], wr, wc, fr, fq, acc);
    __syncthreads();
  }

  const int bx = blockIdx.x;
  if (bx < 2){
    const float* bb = bx ? b2 : b1;
    const float al = bx ? a2[0] : a1[0];
    unsigned short* ex = bx ? e2x : e1x;
#pragma unroll
    for (int m=0;m<4;m++){
#pragma unroll
      for (int n=0;n<4;n++){
        const int c = wc*64 + n*16 + fr;
        const float bias = bb[c];
#pragma unroll
        for (int reg=0;reg<4;reg++){
          const size_t r = (size_t)(m0 + wr*64 + m*16 + fq*4 + reg);
          float u = acc[m][n][reg] + bias;
          u = u >= 0.f ? u : al*u;
          unsigned short h = bf16rn(u);
          unsigned short l = bf16rn(u - bf16tof(h));
          if (bx == 0){            // e1x: [h | l | h]
            ex[r*384 + c] = h; ex[r*384 + 128 + c] = l; ex[r*384 + 256 + c] = h;
          } else {                 // e2x: [h | h | l]
            ex[r*384 + c] = h; ex[r*384 + 128 + c] = h; ex[r*384 + 256 + c] = l;
          }
        }
      }
    }
  } else {
    const float al = aa[0];
#pragma unroll
    for (int m=0;m<4;m++){
#pragma unroll
      for (int n=0;n<4;n++){
        const int c = (bx-2)*128 + wc*64 + n*16 + fr;
        const float bias = ba[c];
#pragma unroll
        for (int reg=0;reg<4;reg++){
          const size_t r = (size_t)(m0 + wr*64 + m*16 + fq*4 + reg);
          float u = acc[m][n][reg] + bias;
          Vf[r*CCH + c] = u >= 0.f ? u : al*u;
        }
      }
    }
  }
}

// ---- QK^T: plain bf16 GEMM over K=384 ([h|l|h] x [h|h|l]) ----
__global__ __launch_bounds__(256) void qk_mfma(
    const unsigned short* __restrict__ e1, const unsigned short* __restrict__ e2,
    float* __restrict__ S)
{
  __shared__ __align__(16) short As[2][128*64];
  __shared__ __align__(16) short Bs[2][128*64];
  const int t = threadIdx.x;
  const int m0 = blockIdx.y*128, n0 = blockIdx.x*128;
  const int wid = t>>6, lane = t&63;
  const int wr = wid>>1, wc = wid&1;
  const int fr = lane&15, fq = lane>>4;
  const int r32 = t>>3, seg = t&7;

  const unsigned short* ap = e1 + (size_t)m0*384;
  const unsigned short* bp = e2 + (size_t)n0*384;

  f32x4 acc[4][4];
#pragma unroll
  for (int m=0;m<4;m++)
#pragma unroll
    for (int n=0;n<4;n++) acc[m][n] = (f32x4){0.f,0.f,0.f,0.f};

  stage_pair(ap, bp, 384, 384, As[0], Bs[0], 0, r32, seg);
  __syncthreads();
#pragma unroll
  for (int s=0;s<6;s++){
    const int cur = s&1;
    if (s<5) stage_pair(ap, bp, 384, 384, As[cur^1], Bs[cur^1], (s+1)*64, r32, seg);
    frag_mfma(As[cur], Bs[cur], wr, wc, fr, fq, acc);
    __syncthreads();
  }
#pragma unroll
  for (int m=0;m<4;m++){
#pragma unroll
    for (int n=0;n<4;n++){
#pragma unroll
      for (int reg=0;reg<4;reg++){
        const int r = m0 + wr*64 + m*16 + fq*4 + reg;
        const int c = n0 + wc*64 + n*16 + fr;
        S[(size_t)r*NN + c] = acc[m][n][reg];
      }
    }
  }
}

// ---- fused sparsemax + sparse PV ----
__global__ __launch_bounds__(256) void spv_kernel(
    const float* __restrict__ S, const float* __restrict__ V,
    const float* __restrict__ xr, float* __restrict__ out)
{
  const int row = blockIdx.x;
  const float4* sp = (const float4*)(S + (size_t)row * NN);
  const int t = threadIdx.x;
  const int lane = t & 63, wid = t >> 6;
  __shared__ float redf[4];
  __shared__ int   redi[4];
  __shared__ int   scan[256];
  __shared__ int   pidx[4096];
  __shared__ float pval[4096];

  float v[16];
  float mx = -1e30f;
#pragma unroll
  for (int j=0;j<4;j++){
    float4 u = sp[256*j + t];
    v[4*j]=u.x; v[4*j+1]=u.y; v[4*j+2]=u.z; v[4*j+3]=u.w;
    mx = fmaxf(mx, fmaxf(fmaxf(u.x,u.y), fmaxf(u.z,u.w)));
  }
  mx = wredMax(mx);
  if (lane==0) redf[wid] = mx;
  __syncthreads();
  mx = fmaxf(fmaxf(redf[0],redf[1]), fmaxf(redf[2],redf[3]));
  __syncthreads();
#pragma unroll
  for (int j=0;j<16;j++) v[j] -= mx;

  // Michelot fixed point from the filtered superset {v > -1} (tau >= max-1)
  float tau = -1.0f;
  int cnt = -1;
  for (int iter=0; iter<128; ++iter){
    float ps = 0.f; int pc = 0;
#pragma unroll
    for (int j=0;j<16;j++) if (v[j] > tau){ ps += v[j]; pc++; }
    ps = wredSum(ps); pc = wredSumI(pc);
    if (lane==0){ redf[wid] = ps; redi[wid] = pc; }
    __syncthreads();
    float S4 = redf[0]+redf[1]+redf[2]+redf[3];
    int   C4 = redi[0]+redi[1]+redi[2]+redi[3];
    __syncthreads();
    tau = (S4 - 1.f) / (float)C4;
    if (C4 == cnt) break;
    cnt = C4;
  }

  // deterministic nonzero extraction via block inclusive scan
  int lc = 0;
#pragma unroll
  for (int j=0;j<16;j++) if (v[j] > tau) lc++;
  scan[t] = lc;
  __syncthreads();
  for (int off=1; off<256; off<<=1){
    int xs_ = (t >= off) ? scan[t-off] : 0;
    __syncthreads();
    scan[t] += xs_;
    __syncthreads();
  }
  const int K = scan[255];
  int o = scan[t] - lc;
#pragma unroll
  for (int j=0;j<16;j++){
    if (v[j] > tau){
      pidx[o] = 1024*(j>>2) + 4*t + (j&3);
      pval[o] = v[j] - tau;
      o++;
    }
  }
  __syncthreads();

  float accv = xr[(size_t)row*CCH + t];
  for (int q=0;q<K;q++)
    accv = fmaf(pval[q], V[(size_t)pidx[q]*CCH + t], accv);
  out[(size_t)row*CCH + t] = accv;
}

extern "C" void kernel_launch(void* const* d_in, const int* in_sizes, int n_in,
                              void* d_out, int out_size, void* d_ws, size_t ws_size,
                              hipStream_t stream) {
  const float* x  = (const float*)d_in[0];
  const float* W1 = (const float*)d_in[1];
  const float* b1 = (const float*)d_in[2];
  const float* a1 = (const float*)d_in[3];
  const float* W2 = (const float*)d_in[4];
  const float* b2 = (const float*)d_in[5];
  const float* a2 = (const float*)d_in[6];
  const float* Wa = (const float*)d_in[7];
  const float* ba = (const float*)d_in[8];
  const float* aa = (const float*)d_in[9];
  float* out = (float*)d_out;

  // ws layout: xs 25.2MB | Wt 0.8MB | e1x 12.6MB | e2x 12.6MB | V 16.8MB | S 67MB  (~135MB)
  unsigned short* xs  = (unsigned short*)d_ws;
  unsigned short* Wt  = xs  + (size_t)16384*768;
  unsigned short* e1x = Wt  + (size_t)512*768;
  unsigned short* e2x = e1x + (size_t)16384*384;
  float* Vf = (float*)(e2x + (size_t)16384*384);
  float* Sb = Vf + (size_t)BB*NN*CCH;

  dim3 blk(256);
  prep_x<<<dim3(2048,1,1), blk, 0, stream>>>(x, xs);
  prep_w<<<dim3(512,1,1), blk, 0, stream>>>(W1, W2, Wa, Wt);
  proj_mfma<<<dim3(4,128,1), blk, 0, stream>>>(xs, Wt, b1,a1, b2,a2, ba,aa,
                                               e1x, e2x, Vf);
  for (int b=0;b<BB;b++){
    const unsigned short* e1b = e1x + (size_t)b*NN*384;
    const unsigned short* e2b = e2x + (size_t)b*NN*384;
    const size_t co = (size_t)b*NN*CCH;
    qk_mfma<<<dim3(32,32,1), blk, 0, stream>>>(e1b, e2b, Sb);
    spv_kernel<<<dim3(NN,1,1), blk, 0, stream>>>(Sb, Vf + co, x + co, out + co);
  }
}

// Round 8
// 225.067 us; speedup vs baseline: 6.6237x; 1.0042x over previous
//
#include <hip/hip_runtime.h>
#include <cstdint>

#define BB 4
#define NN 4096
#define CCH 256

typedef __attribute__((ext_vector_type(8))) short bf16x8;
typedef __attribute__((ext_vector_type(4))) float f32x4;

__device__ __forceinline__ unsigned short bf16rn(float f){
  unsigned u = __float_as_uint(f);
  unsigned r = u + 0x7FFFu + ((u>>16)&1u);
  return (unsigned short)(r>>16);
}
__device__ __forceinline__ float bf16tof(unsigned short h){
  return __uint_as_float(((unsigned)h)<<16);
}
__device__ __forceinline__ void gl_lds16(const void* g, void* l){
  __builtin_amdgcn_global_load_lds(
    (const __attribute__((address_space(1))) void*)g,
    (__attribute__((address_space(3))) void*)l, 16, 0, 0);
}

__device__ __forceinline__ float wredSum(float v){
#pragma unroll
  for (int o=32;o;o>>=1) v += __shfl_down(v,o);
  return v;
}
__device__ __forceinline__ float wredMax(float v){
#pragma unroll
  for (int o=32;o;o>>=1) v = fmaxf(v,__shfl_down(v,o));
  return v;
}
__device__ __forceinline__ int wredSumI(int v){
#pragma unroll
  for (int o=32;o;o>>=1) v += __shfl_down(v,o);
  return v;
}

// ---- prep: split x -> xs [16384][768] bf16 (hi | lo | hi) ----
__global__ __launch_bounds__(256) void prep_x(
    const float* __restrict__ x, unsigned short* __restrict__ xs)
{
  const int stride = gridDim.x * 256;
  for (int idx = blockIdx.x*256 + threadIdx.x; idx < 16384*64; idx += stride){
    const int r = idx >> 6, c4 = (idx & 63) * 4;
    float4 u = *(const float4*)(x + (size_t)r*256 + c4);
    ushort4 h, l;
    h.x=bf16rn(u.x); l.x=bf16rn(u.x - bf16tof(h.x));
    h.y=bf16rn(u.y); l.y=bf16rn(u.y - bf16tof(h.y));
    h.z=bf16rn(u.z); l.z=bf16rn(u.z - bf16tof(h.z));
    h.w=bf16rn(u.w); l.w=bf16rn(u.w - bf16tof(h.w));
    unsigned short* row = xs + (size_t)r*768;
    *(ushort4*)(row + c4)       = h;
    *(ushort4*)(row + 256 + c4) = l;
    *(ushort4*)(row + 512 + c4) = h;
  }
}

// ---- prep: weights -> Wt [512][768] bf16 (hi | hi | lo), rows = output cols ----
__global__ __launch_bounds__(256) void prep_w(
    const float* __restrict__ W1, const float* __restrict__ W2,
    const float* __restrict__ Wa, unsigned short* __restrict__ Wt)
{
  const int n = blockIdx.x;      // 512
  const int k = threadIdx.x;     // 256
  float w = (n < 128) ? W1[(size_t)k*128 + n]
          : (n < 256) ? W2[(size_t)k*128 + (n-128)]
                      : Wa[(size_t)k*256 + (n-256)];
  unsigned short h = bf16rn(w);
  unsigned short l = bf16rn(w - bf16tof(h));
  unsigned short* row = Wt + (size_t)n*768;
  row[k] = h; row[256+k] = h; row[512+k] = l;
}

// ---- fused projection GEMM: 64x128 tile, K=768, single-buffer LDS ----
__global__ __launch_bounds__(256) void proj_mfma(
    const unsigned short* __restrict__ xs, const unsigned short* __restrict__ Wt,
    const float* __restrict__ b1, const float* __restrict__ a1,
    const float* __restrict__ b2, const float* __restrict__ a2,
    const float* __restrict__ ba, const float* __restrict__ aa,
    unsigned short* __restrict__ e1x, unsigned short* __restrict__ e2x,
    float* __restrict__ Vf)
{
  __shared__ __align__(16) short As[64*64];
  __shared__ __align__(16) short Bs[128*64];
  const int t = threadIdx.x;
  const int m0 = blockIdx.y*64, n0 = blockIdx.x*128;
  const int wid = t>>6, lane = t&63;
  const int wr = wid>>1, wc = wid&1;
  const int fr = lane&15, fq = lane>>4;
  const int r32 = t>>3, seg = t&7;

  const unsigned short* ap = xs + (size_t)m0*768;
  const unsigned short* bp = Wt + (size_t)n0*768;

  f32x4 acc[2][4];
#pragma unroll
  for (int m=0;m<2;m++)
#pragma unroll
    for (int n=0;n<4;n++) acc[m][n] = (f32x4){0.f,0.f,0.f,0.f};

#pragma unroll
  for (int s=0;s<12;s++){
    const int kk = s*64;
#pragma unroll
    for (int i=0;i<2;i++){
      const int rowL = r32 + i*32;
      const int sw = (seg ^ (rowL & 7)) * 8;
      gl_lds16(ap + (size_t)rowL*768 + kk + sw, &As[rowL*64 + seg*8]);
    }
#pragma unroll
    for (int i=0;i<4;i++){
      const int rowL = r32 + i*32;
      const int sw = (seg ^ (rowL & 7)) * 8;
      gl_lds16(bp + (size_t)rowL*768 + kk + sw, &Bs[rowL*64 + seg*8]);
    }
    __syncthreads();
    bf16x8 af[2][2], bf[4][2];
#pragma unroll
    for (int m=0;m<2;m++){
      const int ar_ = wr*32 + m*16 + fr;
#pragma unroll
      for (int ks=0;ks<2;ks++)
        af[m][ks] = *(const bf16x8*)&As[ar_*64 + (((ks*4+fq) ^ (ar_&7))*8)];
    }
#pragma unroll
    for (int n=0;n<4;n++){
      const int br_ = wc*64 + n*16 + fr;
#pragma unroll
      for (int ks=0;ks<2;ks++)
        bf[n][ks] = *(const bf16x8*)&Bs[br_*64 + (((ks*4+fq) ^ (br_&7))*8)];
    }
#pragma unroll
    for (int m=0;m<2;m++)
#pragma unroll
      for (int n=0;n<4;n++)
#pragma unroll
        for (int ks=0;ks<2;ks++)
          acc[m][n] = __builtin_amdgcn_mfma_f32_16x16x32_bf16(af[m][ks], bf[n][ks], acc[m][n], 0,0,0);
    __syncthreads();
  }

  const int bx = blockIdx.x;
  if (bx < 2){
    const float* bb = bx ? b2 : b1;
    const float al = bx ? a2[0] : a1[0];
    unsigned short* ex = bx ? e2x : e1x;
#pragma unroll
    for (int m=0;m<2;m++){
#pragma unroll
      for (int n=0;n<4;n++){
        const int c = wc*64 + n*16 + fr;
        const float bias = bb[c];
#pragma unroll
        for (int reg=0;reg<4;reg++){
          const size_t r = (size_t)(m0 + wr*32 + m*16 + fq*4 + reg);
          float u = acc[m][n][reg] + bias;
          u = u >= 0.f ? u : al*u;
          unsigned short h = bf16rn(u);
          unsigned short l = bf16rn(u - bf16tof(h));
          if (bx == 0){            // e1x: [h | l | h]
            ex[r*384 + c] = h; ex[r*384 + 128 + c] = l; ex[r*384 + 256 + c] = h;
          } else {                 // e2x: [h | h | l]
            ex[r*384 + c] = h; ex[r*384 + 128 + c] = h; ex[r*384 + 256 + c] = l;
          }
        }
      }
    }
  } else {
    const float al = aa[0];
#pragma unroll
    for (int m=0;m<2;m++){
#pragma unroll
      for (int n=0;n<4;n++){
        const int c = (bx-2)*128 + wc*64 + n*16 + fr;
        const float bias = ba[c];
#pragma unroll
        for (int reg=0;reg<4;reg++){
          const size_t r = (size_t)(m0 + wr*32 + m*16 + fq*4 + reg);
          float u = acc[m][n][reg] + bias;
          Vf[r*CCH + c] = u >= 0.f ? u : al*u;
        }
      }
    }
  }
}

// ---- QK^T: plain bf16 GEMM K=384, single-buffer, grid (32,32,NB) ----
__global__ __launch_bounds__(256) void qk_mfma(
    const unsigned short* __restrict__ e1base, const unsigned short* __restrict__ e2base,
    float* __restrict__ Sbase)
{
  __shared__ __align__(16) short As[128*64];
  __shared__ __align__(16) short Bs[128*64];
  const int t = threadIdx.x;
  const int z = blockIdx.z;
  const int m0 = blockIdx.y*128, n0 = blockIdx.x*128;
  const int wid = t>>6, lane = t&63;
  const int wr = wid>>1, wc = wid&1;
  const int fr = lane&15, fq = lane>>4;
  const int r32 = t>>3, seg = t&7;

  const unsigned short* ap = e1base + (size_t)z*NN*384 + (size_t)m0*384;
  const unsigned short* bp = e2base + (size_t)z*NN*384 + (size_t)n0*384;
  float* S = Sbase + (size_t)z*NN*NN;

  f32x4 acc[4][4];
#pragma unroll
  for (int m=0;m<4;m++)
#pragma unroll
    for (int n=0;n<4;n++) acc[m][n] = (f32x4){0.f,0.f,0.f,0.f};

#pragma unroll
  for (int s=0;s<6;s++){
    const int kk = s*64;
#pragma unroll
    for (int i=0;i<4;i++){
      const int rowL = r32 + i*32;
      const int sw = (seg ^ (rowL & 7)) * 8;
      gl_lds16(ap + (size_t)rowL*384 + kk + sw, &As[rowL*64 + seg*8]);
      gl_lds16(bp + (size_t)rowL*384 + kk + sw, &Bs[rowL*64 + seg*8]);
    }
    __syncthreads();
    bf16x8 af[4][2], bf[4][2];
#pragma unroll
    for (int m=0;m<4;m++){
      const int ar_ = wr*64 + m*16 + fr;
#pragma unroll
      for (int ks=0;ks<2;ks++)
        af[m][ks] = *(const bf16x8*)&As[ar_*64 + (((ks*4+fq) ^ (ar_&7))*8)];
    }
#pragma unroll
    for (int n=0;n<4;n++){
      const int br_ = wc*64 + n*16 + fr;
#pragma unroll
      for (int ks=0;ks<2;ks++)
        bf[n][ks] = *(const bf16x8*)&Bs[br_*64 + (((ks*4+fq) ^ (br_&7))*8)];
    }
#pragma unroll
    for (int m=0;m<4;m++)
#pragma unroll
      for (int n=0;n<4;n++)
#pragma unroll
        for (int ks=0;ks<2;ks++)
          acc[m][n] = __builtin_amdgcn_mfma_f32_16x16x32_bf16(af[m][ks], bf[n][ks], acc[m][n], 0,0,0);
    __syncthreads();
  }
#pragma unroll
  for (int m=0;m<4;m++){
#pragma unroll
    for (int n=0;n<4;n++){
#pragma unroll
      for (int reg=0;reg<4;reg++){
        const int r = m0 + wr*64 + m*16 + fq*4 + reg;
        const int c = n0 + wc*64 + n*16 + fr;
        S[(size_t)r*NN + c] = acc[m][n][reg];
      }
    }
  }
}

// ---- fused sparsemax + sparse PV; row global over batches (b = row>>12) ----
__global__ __launch_bounds__(256) void spv_kernel(
    const float* __restrict__ S, const float* __restrict__ V,
    const float* __restrict__ xr, float* __restrict__ out)
{
  const int row = blockIdx.x;
  const int b = row >> 12;
  const float4* sp = (const float4*)(S + (size_t)row * NN);
  const int t = threadIdx.x;
  const int lane = t & 63, wid = t >> 6;
  __shared__ float redf[4];
  __shared__ int   redi[4];
  __shared__ int   scan[256];
  __shared__ int   pidx[4096];
  __shared__ float pval[4096];

  float v[16];
  float mx = -1e30f;
#pragma unroll
  for (int j=0;j<4;j++){
    float4 u = sp[256*j + t];
    v[4*j]=u.x; v[4*j+1]=u.y; v[4*j+2]=u.z; v[4*j+3]=u.w;
    mx = fmaxf(mx, fmaxf(fmaxf(u.x,u.y), fmaxf(u.z,u.w)));
  }
  mx = wredMax(mx);
  if (lane==0) redf[wid] = mx;
  __syncthreads();
  mx = fmaxf(fmaxf(redf[0],redf[1]), fmaxf(redf[2],redf[3]));
  __syncthreads();
#pragma unroll
  for (int j=0;j<16;j++) v[j] -= mx;

  // Michelot fixed point from the filtered superset {v > -1} (tau >= max-1)
  float tau = -1.0f;
  int cnt = -1;
  for (int iter=0; iter<128; ++iter){
    float ps = 0.f; int pc = 0;
#pragma unroll
    for (int j=0;j<16;j++) if (v[j] > tau){ ps += v[j]; pc++; }
    ps = wredSum(ps); pc = wredSumI(pc);
    if (lane==0){ redf[wid] = ps; redi[wid] = pc; }
    __syncthreads();
    float S4 = redf[0]+redf[1]+redf[2]+redf[3];
    int   C4 = redi[0]+redi[1]+redi[2]+redi[3];
    __syncthreads();
    tau = (S4 - 1.f) / (float)C4;
    if (C4 == cnt) break;
    cnt = C4;
  }

  // deterministic nonzero extraction via block inclusive scan
  int lc = 0;
#pragma unroll
  for (int j=0;j<16;j++) if (v[j] > tau) lc++;
  scan[t] = lc;
  __syncthreads();
  for (int off=1; off<256; off<<=1){
    int xs_ = (t >= off) ? scan[t-off] : 0;
    __syncthreads();
    scan[t] += xs_;
    __syncthreads();
  }
  const int K = scan[255];
  int o = scan[t] - lc;
#pragma unroll
  for (int j=0;j<16;j++){
    if (v[j] > tau){
      pidx[o] = 1024*(j>>2) + 4*t + (j&3);
      pval[o] = v[j] - tau;
      o++;
    }
  }
  __syncthreads();

  float accv = xr[(size_t)row*CCH + t];
  const float* Vb = V + ((size_t)b << 12) * CCH;
  for (int q=0;q<K;q++)
    accv = fmaf(pval[q], Vb[(size_t)pidx[q]*CCH + t], accv);
  out[(size_t)row*CCH + t] = accv;
}

extern "C" void kernel_launch(void* const* d_in, const int* in_sizes, int n_in,
                              void* d_out, int out_size, void* d_ws, size_t ws_size,
                              hipStream_t stream) {
  const float* x  = (const float*)d_in[0];
  const float* W1 = (const float*)d_in[1];
  const float* b1 = (const float*)d_in[2];
  const float* a1 = (const float*)d_in[3];
  const float* W2 = (const float*)d_in[4];
  const float* b2 = (const float*)d_in[5];
  const float* a2 = (const float*)d_in[6];
  const float* Wa = (const float*)d_in[7];
  const float* ba = (const float*)d_in[8];
  const float* aa = (const float*)d_in[9];
  float* out = (float*)d_out;

  // ws: xs 25.2MB | Wt 0.8MB | e1x 12.6MB | e2x 12.6MB | V 16.8MB | S ...
  unsigned short* xs  = (unsigned short*)d_ws;
  unsigned short* Wt  = xs  + (size_t)16384*768;
  unsigned short* e1x = Wt  + (size_t)512*768;
  unsigned short* e2x = e1x + (size_t)16384*384;
  float* Vf = (float*)(e2x + (size_t)16384*384);
  float* Sb = Vf + (size_t)BB*NN*CCH;

  const size_t bytesHead = ((size_t)16384*768 + (size_t)512*768
                          + (size_t)2*16384*384) * 2 + (size_t)BB*NN*CCH*4;
  const bool batched = ws_size >= bytesHead + (size_t)BB*NN*NN*4;

  dim3 blk(256);
  prep_x<<<dim3(2048,1,1), blk, 0, stream>>>(x, xs);
  prep_w<<<dim3(512,1,1), blk, 0, stream>>>(W1, W2, Wa, Wt);
  proj_mfma<<<dim3(4,256,1), blk, 0, stream>>>(xs, Wt, b1,a1, b2,a2, ba,aa,
                                               e1x, e2x, Vf);
  if (batched){
    qk_mfma<<<dim3(32,32,BB), blk, 0, stream>>>(e1x, e2x, Sb);
    spv_kernel<<<dim3(BB*NN,1,1), blk, 0, stream>>>(Sb, Vf, x, out);
  } else {
    for (int b=0;b<BB;b++){
      const size_t co = (size_t)b*NN*CCH;
      qk_mfma<<<dim3(32,32,1), blk, 0, stream>>>(
          e1x + (size_t)b*NN*384, e2x + (size_t)b*NN*384, Sb);
      spv_kernel<<<dim3(NN,1,1), blk, 0, stream>>>(Sb, Vf + co, x + co, out + co);
    }
  }
}